// Round 1
// baseline (604.172 us; speedup 1.0000x reference)
//
#include <hip/hip_runtime.h>
#include <hip/hip_fp16.h>
#include <cmath>

typedef _Float16 f16x8 __attribute__((ext_vector_type(8)));
typedef _Float16 f16x4 __attribute__((ext_vector_type(4)));
typedef float f32x4 __attribute__((ext_vector_type(4)));

#define NV 32000
#define NE 256
#define NH 512
#define NL 2
#define NB 64
#define NT 2048

// ---------------- prep kernels ----------------

// WaT[h*512 + n] = W_attn[n*1024 + h]   (first-half columns, fp32)
__global__ void k_transpose_wa(const float* __restrict__ src, float* __restrict__ dst) {
  __shared__ float tile[32][33];
  int r0 = blockIdx.y << 5, c0 = blockIdx.x << 5;
  int x = threadIdx.x, y = threadIdx.y;
  #pragma unroll
  for (int i = y; i < 32; i += 8) tile[i][x] = src[(r0 + i) * 1024 + c0 + x];
  __syncthreads();
  #pragma unroll
  for (int i = y; i < 32; i += 8) dst[(c0 + i) * 512 + r0 + x] = tile[x][i];
}

// dst[c*R + r] = (f16) src[r*C + c]
__global__ void k_transpose_f16(const float* __restrict__ src, _Float16* __restrict__ dst,
                                int R, int C) {
  __shared__ float tile[32][33];
  int r0 = blockIdx.y << 5, c0 = blockIdx.x << 5;
  int x = threadIdx.x, y = threadIdx.y;
  for (int i = y; i < 32; i += 8) tile[i][x] = src[(long)(r0 + i) * C + c0 + x];
  __syncthreads();
  for (int i = y; i < 32; i += 8) dst[(long)(c0 + i) * R + r0 + x] = (_Float16)tile[x][i];
}

// Be fragment-swizzled fp16: element for (lane l, reg j) of n-tile nt, k-chunk kc:
//   B[h][n] = W_attn[n][512+h],  h = kc*32 + (l>>4)*8 + j,  n = nt*16 + (l&15)
//   stored at ((kc*32 + nt)*64 + l)*8 + j
__global__ void k_swz_be(const float* __restrict__ Wattn, _Float16* __restrict__ Be) {
  int idx = blockIdx.x * 256 + threadIdx.x;   // 0..32767
  int l = idx & 63, nt = (idx >> 6) & 31, kc = idx >> 11;
  int n = (nt << 4) + (l & 15);
  int h0 = (kc << 5) + ((l >> 4) << 3);
  const float* s = Wattn + n * 1024 + 512 + h0;
  _Float16* d = Be + idx * 8;
  #pragma unroll
  for (int j = 0; j < 8; ++j) d[j] = (_Float16)s[j];
}

// hp[b][n] = h0[1][b]·W_attn[n][0:512] + b_attn[n]
__global__ void k_hpart(const float* __restrict__ WaT, const float* __restrict__ h0,
                        const float* __restrict__ battn, float* __restrict__ hp) {
  __shared__ float ht[NH];
  int b = blockIdx.x, n = threadIdx.x;
  ht[n] = h0[NB * NH + b * NH + n];
  __syncthreads();
  float acc = battn[n];
  #pragma unroll 8
  for (int h = 0; h < NH; ++h) acc = fmaf(ht[h], WaT[h * NH + n], acc);
  hp[b * NH + n] = acc;
}

// ---------------- energy: fused MFMA GEMM + tanh + v-reduce ----------------
// tile = 64 enc rows x all 512 cols; 8 waves, wave w owns cols [w*64, w*64+64)
__global__ __launch_bounds__(512)
void k_energy(const float* __restrict__ enc, const _Float16* __restrict__ Be,
              const float* __restrict__ hp, const float* __restrict__ vat,
              float* __restrict__ eng) {
  __shared__ _Float16 A[64 * 264];       // 64 rows x 256 k (per phase), pad 8
  __shared__ float hpl[NH], vl[NH], ep[64][8];
  int tile = blockIdx.x;                 // 0..2047
  int b = tile >> 5;                     // 32 tiles per batch row
  long row0 = (long)tile << 6;
  int tid = threadIdx.x;
  hpl[tid] = hp[(b << 9) + tid];
  vl[tid] = vat[tid];
  const float* Ab = enc + row0 * NH;
  int w = tid >> 6, l = tid & 63;
  f32x4 acc[4][4];
  #pragma unroll
  for (int mi = 0; mi < 4; ++mi)
    #pragma unroll
    for (int ni = 0; ni < 4; ++ni) acc[mi][ni] = (f32x4){0.f, 0.f, 0.f, 0.f};

  for (int ph = 0; ph < 2; ++ph) {
    __syncthreads();
    // stage 64x256 fp32 -> fp16 LDS (coalesced float4)
    #pragma unroll
    for (int i = 0; i < 8; ++i) {
      int s = tid + (i << 9);
      int r = s >> 6, k4 = s & 63;
      float4 v4 = *(const float4*)(Ab + r * NH + (ph << 8) + (k4 << 2));
      f16x4 h4 = {(_Float16)v4.x, (_Float16)v4.y, (_Float16)v4.z, (_Float16)v4.w};
      *(f16x4*)(A + r * 264 + (k4 << 2)) = h4;
    }
    __syncthreads();
    for (int kc = 0; kc < 8; ++kc) {
      int kcg = (ph << 3) + kc;
      f16x8 a[4], bf[4];
      #pragma unroll
      for (int mi = 0; mi < 4; ++mi)
        a[mi] = *(const f16x8*)(A + (mi * 16 + (l & 15)) * 264 + (kc << 5) + ((l >> 4) << 3));
      #pragma unroll
      for (int ni = 0; ni < 4; ++ni)
        bf[ni] = *(const f16x8*)(Be + (size_t)((((kcg << 5) + (w << 2) + ni) << 6) + l) * 8);
      #pragma unroll
      for (int mi = 0; mi < 4; ++mi)
        #pragma unroll
        for (int ni = 0; ni < 4; ++ni)
          acc[mi][ni] = __builtin_amdgcn_mfma_f32_16x16x32_f16(a[mi], bf[ni], acc[mi][ni], 0, 0, 0);
    }
  }
  // epilogue: energy[row] = sum_col v[col]*tanh(acc + hp[col])
  int cl = l & 15;
  #pragma unroll
  for (int mi = 0; mi < 4; ++mi) {
    float s0 = 0.f, s1 = 0.f, s2 = 0.f, s3 = 0.f;
    #pragma unroll
    for (int ni = 0; ni < 4; ++ni) {
      int col = (w << 6) + (ni << 4) + cl;
      float hv = hpl[col], vv = vl[col];
      s0 += vv * tanhf(acc[mi][ni][0] + hv);
      s1 += vv * tanhf(acc[mi][ni][1] + hv);
      s2 += vv * tanhf(acc[mi][ni][2] + hv);
      s3 += vv * tanhf(acc[mi][ni][3] + hv);
    }
    #pragma unroll
    for (int off = 1; off < 16; off <<= 1) {
      s0 += __shfl_xor(s0, off, 64);
      s1 += __shfl_xor(s1, off, 64);
      s2 += __shfl_xor(s2, off, 64);
      s3 += __shfl_xor(s3, off, 64);
    }
    if (cl == 0) {
      int rb = mi * 16 + ((l >> 4) << 2);
      ep[rb][w] = s0; ep[rb + 1][w] = s1; ep[rb + 2][w] = s2; ep[rb + 3][w] = s3;
    }
  }
  __syncthreads();
  if (tid < 64) {
    float e = 0.f;
    #pragma unroll
    for (int q = 0; q < 8; ++q) e += ep[tid][q];
    eng[row0 + tid] = e;
  }
}

// ---------------- softmax over T with mask ----------------
__global__ void k_softmax(const float* __restrict__ eng, const int* __restrict__ mask,
                          float* __restrict__ attw) {
  __shared__ float red[4], reds[4];
  int b = blockIdx.x, tid = threadIdx.x;   // 256 threads
  float v[8];
  float mx = -3.4e38f;
  #pragma unroll
  for (int i = 0; i < 8; ++i) {
    int t = tid + (i << 8);
    float e = eng[(b << 11) + t];
    v[i] = mask[(b << 11) + t] ? e : -3.4e38f;
    mx = fmaxf(mx, v[i]);
  }
  #pragma unroll
  for (int off = 1; off < 64; off <<= 1) mx = fmaxf(mx, __shfl_xor(mx, off, 64));
  if ((tid & 63) == 0) red[tid >> 6] = mx;
  __syncthreads();
  mx = fmaxf(fmaxf(red[0], red[1]), fmaxf(red[2], red[3]));
  float p[8], sum = 0.f;
  #pragma unroll
  for (int i = 0; i < 8; ++i) { p[i] = expf(v[i] - mx); sum += p[i]; }
  #pragma unroll
  for (int off = 1; off < 64; off <<= 1) sum += __shfl_xor(sum, off, 64);
  if ((tid & 63) == 0) reds[tid >> 6] = sum;
  __syncthreads();
  sum = reds[0] + reds[1] + reds[2] + reds[3];
  float r = 1.f / sum;
  #pragma unroll
  for (int i = 0; i < 8; ++i) {
    int t = tid + (i << 8);
    attw[(b << 11) + t] = p[i] * r;
  }
}

// ---------------- context = sum_t w[b,t]*enc[b,t,:]  (2-stage) ----------------
__global__ void k_ctx1(const float* __restrict__ enc, const float* __restrict__ wgt,
                       float* __restrict__ part) {
  __shared__ float wl[128];
  int b = blockIdx.x >> 4, tc = blockIdx.x & 15;
  int tid = threadIdx.x;   // 256
  if (tid < 128) wl[tid] = wgt[(b << 11) + (tc << 7) + tid];
  __syncthreads();
  int p = tid >> 7, c4 = tid & 127;
  float4 a = {0.f, 0.f, 0.f, 0.f};
  const float4* eb = (const float4*)(enc + ((long)(b << 11) + (tc << 7)) * NH);
  for (int i = 0; i < 64; ++i) {
    int t = (i << 1) + p;
    float wv = wl[t];
    float4 ev = eb[t * 128 + c4];
    a.x += wv * ev.x; a.y += wv * ev.y; a.z += wv * ev.z; a.w += wv * ev.w;
  }
  ((float4*)part)[(((b << 5) + (tc << 1) + p) << 7) + c4] = a;
}

__global__ void k_ctx2(const float* __restrict__ part, float* __restrict__ ctx) {
  int idx = blockIdx.x * 256 + threadIdx.x;   // 32768
  int b = idx >> 9, h = idx & 511;
  float s = 0.f;
  #pragma unroll 8
  for (int q = 0; q < 32; ++q) s += part[(((b << 5) + q) << 9) + h];
  ctx[idx] = s;
}

// ---------------- fused LSTM step (gates GEMV + cell) ----------------
// grid: 64 b x 16 u-chunks; 128 threads = 32 units x 4 gates
template <int KX>
__global__ void k_lstm(const float* __restrict__ emb, const int* __restrict__ token,
                       const float* __restrict__ ctx, const float* __restrict__ xv,
                       const float* __restrict__ hprev, const float* __restrict__ cprev,
                       const _Float16* __restrict__ WiT, const _Float16* __restrict__ WhT,
                       const float* __restrict__ bih, const float* __restrict__ bhh,
                       float* __restrict__ hout, float* __restrict__ cout) {
  __shared__ float xl[KX + NH];
  __shared__ float gl[4][32];
  int b = blockIdx.x >> 4, uc = blockIdx.x & 15;
  int tid = threadIdx.x;   // 128
  if (KX == 768) {
    int tok = token[b];
    for (int i = tid; i < NE; i += 128) xl[i] = emb[tok * NE + i];
    for (int i = tid; i < NH; i += 128) xl[NE + i] = ctx[(b << 9) + i];
  } else {
    for (int i = tid; i < NH; i += 128) xl[i] = xv[(b << 9) + i];
  }
  for (int i = tid; i < NH; i += 128) xl[KX + i] = hprev[(b << 9) + i];
  __syncthreads();
  int gi = tid >> 5, ui = tid & 31;
  int j = (gi << 9) + (uc << 5) + ui;     // gate-major row in [4H]
  float g = bih[j] + bhh[j];
  const _Float16* wp = WiT + j;
  #pragma unroll 4
  for (int k = 0; k < KX; ++k) g = fmaf(xl[k], (float)wp[(size_t)k * 2048], g);
  const _Float16* wh = WhT + j;
  #pragma unroll 4
  for (int k = 0; k < NH; ++k) g = fmaf(xl[KX + k], (float)wh[(size_t)k * 2048], g);
  gl[gi][ui] = g;
  __syncthreads();
  if (tid < 32) {
    int u = (uc << 5) + tid;
    float ig = 1.f / (1.f + expf(-gl[0][tid]));
    float fg = 1.f / (1.f + expf(-gl[1][tid]));
    float gg = tanhf(gl[2][tid]);
    float og = 1.f / (1.f + expf(-gl[3][tid]));
    float c = fg * cprev[(b << 9) + u] + ig * gg;
    float h = og * tanhf(c);
    cout[(b << 9) + u] = c;
    hout[(b << 9) + u] = h;
  }
}

// ---------------- logits = h1 @ W_out^T + b_out  (fp32 tiled GEMM) ----------------
// WG: 128 v-rows x 64 b; 256 threads: tid = bi*16+vi; thread owns 4 b x 8 v
__global__ __launch_bounds__(256)
void k_logits(const float* __restrict__ h1, const float* __restrict__ Wout,
              const float* __restrict__ bout, float* __restrict__ out) {
  __shared__ float Wc[128 * 68];
  __shared__ float hc[64 * 68];
  int vt0 = blockIdx.x << 7;
  int tid = threadIdx.x;
  int bi = tid >> 4, vi = tid & 15;
  float acc[4][8];
  #pragma unroll
  for (int bb = 0; bb < 4; ++bb)
    #pragma unroll
    for (int jj = 0; jj < 8; ++jj) acc[bb][jj] = 0.f;
  for (int kc = 0; kc < 8; ++kc) {
    __syncthreads();
    #pragma unroll
    for (int i = 0; i < 8; ++i) {
      int s = tid + (i << 8);        // 2048 float4 slots
      int r = s >> 4, k4 = s & 15;
      float4 wv = *(const float4*)(Wout + (long)(vt0 + r) * NH + (kc << 6) + (k4 << 2));
      *(float4*)&Wc[r * 68 + (k4 << 2)] = wv;
    }
    #pragma unroll
    for (int i = 0; i < 4; ++i) {
      int s = tid + (i << 8);        // 1024 float4 slots
      int r = s >> 4, k4 = s & 15;
      float4 hv = *(const float4*)(h1 + (r << 9) + (kc << 6) + (k4 << 2));
      *(float4*)&hc[r * 68 + (k4 << 2)] = hv;
    }
    __syncthreads();
    for (int kk = 0; kk < 16; ++kk) {
      float4 hv[4], wv[8];
      #pragma unroll
      for (int bb = 0; bb < 4; ++bb) hv[bb] = *(const float4*)&hc[((bi << 2) + bb) * 68 + (kk << 2)];
      #pragma unroll
      for (int jj = 0; jj < 8; ++jj) wv[jj] = *(const float4*)&Wc[(vi + (jj << 4)) * 68 + (kk << 2)];
      #pragma unroll
      for (int bb = 0; bb < 4; ++bb)
        #pragma unroll
        for (int jj = 0; jj < 8; ++jj)
          acc[bb][jj] += hv[bb].x * wv[jj].x + hv[bb].y * wv[jj].y +
                         hv[bb].z * wv[jj].z + hv[bb].w * wv[jj].w;
    }
  }
  #pragma unroll
  for (int bb = 0; bb < 4; ++bb)
    #pragma unroll
    for (int jj = 0; jj < 8; ++jj) {
      int v = vt0 + vi + (jj << 4);
      out[(long)((bi << 2) + bb) * NV + v] = acc[bb][jj] + bout[v];
    }
}

// ---------------- launch ----------------
extern "C" void kernel_launch(void* const* d_in, const int* in_sizes, int n_in,
                              void* d_out, int out_size, void* d_ws, size_t ws_size,
                              hipStream_t stream) {
  (void)in_sizes; (void)n_in; (void)out_size; (void)ws_size;
  const int*   token = (const int*)d_in[0];
  const float* h0    = (const float*)d_in[1];
  const float* c0    = (const float*)d_in[2];
  const float* enc   = (const float*)d_in[3];
  const int*   mask  = (const int*)d_in[4];
  const float* emb   = (const float*)d_in[5];
  const float* Wattn = (const float*)d_in[6];
  const float* battn = (const float*)d_in[7];
  const float* vattn = (const float*)d_in[8];
  const float* Wih0  = (const float*)d_in[9];
  const float* Whh0  = (const float*)d_in[10];
  const float* bih0  = (const float*)d_in[11];
  const float* bhh0  = (const float*)d_in[12];
  const float* Wih1  = (const float*)d_in[13];
  const float* Whh1  = (const float*)d_in[14];
  const float* bih1  = (const float*)d_in[15];
  const float* bhh1  = (const float*)d_in[16];
  const float* Wout  = (const float*)d_in[17];
  const float* bout  = (const float*)d_in[18];

  // workspace layout (~15.3 MB)
  float* ws   = (float*)d_ws;
  float* WaT  = ws;                       // 512*512
  float* hp   = WaT + 262144;             // 64*512
  float* eng  = hp + 32768;               // 131072
  float* part = eng + 131072;             // 64*32*512
  float* ctx  = part + 1048576;           // 64*512
  _Float16* Be   = (_Float16*)(ctx + 32768);  // 512*512
  _Float16* WiT0 = Be + 262144;           // 768*2048
  _Float16* WhT0 = WiT0 + 768 * 2048;     // 512*2048
  _Float16* WiT1 = WhT0 + 512 * 2048;
  _Float16* WhT1 = WiT1 + 512 * 2048;

  float* out    = (float*)d_out;
  float* logits = out;                          // 64*32000
  float* hnew   = out + (size_t)NB * NV;        // 2*64*512
  float* cnew   = hnew + NL * NB * NH;
  float* attw   = cnew + NL * NB * NH;          // 64*2048

  k_transpose_wa<<<dim3(16, 16), dim3(32, 8), 0, stream>>>(Wattn, WaT);
  k_swz_be<<<dim3(128), dim3(256), 0, stream>>>(Wattn, Be);
  k_transpose_f16<<<dim3(24, 64), dim3(32, 8), 0, stream>>>(Wih0, WiT0, 2048, 768);
  k_transpose_f16<<<dim3(16, 64), dim3(32, 8), 0, stream>>>(Whh0, WhT0, 2048, 512);
  k_transpose_f16<<<dim3(16, 64), dim3(32, 8), 0, stream>>>(Wih1, WiT1, 2048, 512);
  k_transpose_f16<<<dim3(16, 64), dim3(32, 8), 0, stream>>>(Whh1, WhT1, 2048, 512);
  k_hpart<<<dim3(64), dim3(512), 0, stream>>>(WaT, h0, battn, hp);
  k_energy<<<dim3(2048), dim3(512), 0, stream>>>(enc, Be, hp, vattn, eng);
  k_softmax<<<dim3(64), dim3(256), 0, stream>>>(eng, mask, attw);
  k_ctx1<<<dim3(1024), dim3(256), 0, stream>>>(enc, attw, part);
  k_ctx2<<<dim3(128), dim3(256), 0, stream>>>(part, ctx);
  k_lstm<768><<<dim3(1024), dim3(128), 0, stream>>>(
      emb, token, ctx, nullptr, h0, c0, WiT0, WhT0, bih0, bhh0, hnew, cnew);
  k_lstm<512><<<dim3(1024), dim3(128), 0, stream>>>(
      nullptr, nullptr, nullptr, hnew, h0 + NB * NH, c0 + NB * NH,
      WiT1, WhT1, bih1, bhh1, hnew + NB * NH, cnew + NB * NH);
  k_logits<<<dim3(250), dim3(256), 0, stream>>>(hnew + NB * NH, Wout, bout, logits);
}

// Round 3
// 193.593 us; speedup vs baseline: 3.1208x; 3.1208x over previous
//
#include <hip/hip_runtime.h>
#include <hip/hip_fp16.h>
#include <cmath>

typedef _Float16 f16x8 __attribute__((ext_vector_type(8)));
typedef _Float16 f16x4 __attribute__((ext_vector_type(4)));
typedef float f32x4 __attribute__((ext_vector_type(4)));

#define NV 32000
#define NE 256
#define NH 512
#define NB 64
#define NT 2048

__device__ __forceinline__ float fast_tanh(float x) {
  return 1.f - 2.f / (__expf(2.f * x) + 1.f);
}
__device__ __forceinline__ float fast_sig(float x) {
  return 1.f / (1.f + __expf(-x));
}

// ---------- Be fragment-swizzle (W_attn second half -> f16 frags) ----------
// layout [kc(16)][nt(32)][lane(64)][reg(8)]: B[h][n]=W_attn[n][512+h],
// h = kc*32 + (l>>4)*8 + reg, n = nt*16 + (l&15)
__global__ void k_swz_be(const float* __restrict__ Wattn, _Float16* __restrict__ Be) {
  int idx = blockIdx.x * 256 + threadIdx.x;   // 0..32767
  int l = idx & 63, nt = (idx >> 6) & 31, kc = idx >> 11;
  int n = (nt << 4) + (l & 15);
  int h0 = (kc << 5) + ((l >> 4) << 3);
  const float* s = Wattn + n * 1024 + 512 + h0;
  _Float16* d = Be + idx * 8;
  #pragma unroll
  for (int j = 0; j < 8; ++j) d[j] = (_Float16)s[j];
}

// ---------- htop f16 (+ xcat1 second half) ----------
__global__ void k_prep_htop(const float* __restrict__ h0, _Float16* __restrict__ xh,
                            _Float16* __restrict__ xcat1) {
  int b = blockIdx.x, t = threadIdx.x;   // 512 thr
  _Float16 v = (_Float16)h0[NB * NH + b * NH + t];
  xh[b * NH + t] = v;
  xcat1[b * 1024 + 512 + t] = v;
}

// ---------- generic MFMA GEMM: C_part[kcid] = A(f16 [64xK]) x B(f32 rows)^T ----------
// block = 128 thr (2 waves, wave per 16-col group); grid = (N/32) * kchunks
template <int KLEN>
__global__ __launch_bounds__(128)
void k_gemm_bT(const _Float16* __restrict__ A, int K,
               const float* __restrict__ B0, int ldb0,
               const float* __restrict__ B1, int ldb1, int b1k,
               const float* __restrict__ bias,
               float* __restrict__ out, int N) {
  int ntiles = N >> 5;
  int bn = blockIdx.x % ntiles, kcid = blockIdx.x / ntiles;
  int tid = threadIdx.x, w = tid >> 6, l = tid & 63;
  int n = (bn << 5) + (w << 4) + (l & 15);
  int kq = (l >> 4) << 3;
  int k0 = kcid * KLEN;
  f32x4 acc[4];
  #pragma unroll
  for (int mi = 0; mi < 4; ++mi) acc[mi] = (f32x4){0.f, 0.f, 0.f, 0.f};
  #pragma unroll 2
  for (int kk = 0; kk < KLEN; kk += 32) {
    int kbase = k0 + kk;
    f16x8 a[4];
    #pragma unroll
    for (int mi = 0; mi < 4; ++mi)
      a[mi] = *(const f16x8*)(A + (size_t)((l & 15) + (mi << 4)) * K + kbase + kq);
    const float* bp;
    if (B1 && kbase >= b1k) bp = B1 + (size_t)n * ldb1 + (kbase - b1k) + kq;
    else                    bp = B0 + (size_t)n * ldb0 + kbase + kq;
    float4 x0 = *(const float4*)bp;
    float4 x1 = *(const float4*)(bp + 4);
    f16x8 bf = {(_Float16)x0.x, (_Float16)x0.y, (_Float16)x0.z, (_Float16)x0.w,
                (_Float16)x1.x, (_Float16)x1.y, (_Float16)x1.z, (_Float16)x1.w};
    #pragma unroll
    for (int mi = 0; mi < 4; ++mi)
      acc[mi] = __builtin_amdgcn_mfma_f32_16x16x32_f16(a[mi], bf, acc[mi], 0, 0, 0);
  }
  float* op = out + (size_t)kcid * 64 * N;
  #pragma unroll
  for (int mi = 0; mi < 4; ++mi)
    #pragma unroll
    for (int r = 0; r < 4; ++r) {
      int row = (mi << 4) + ((l >> 4) << 2) + r;
      float v = acc[mi][r];
      if (bias) v += bias[n];
      op[(size_t)row * N + n] = v;
    }
}

// ---------- fused energy + online-softmax partials + context partials ----------
// block = 512 thr (8 waves), tile = 64 enc rows x 512 cols, full K=512 in LDS
__global__ __launch_bounds__(512, 4)
void k_energy(const float* __restrict__ enc, const _Float16* __restrict__ Be,
              const float* __restrict__ hp0, const float* __restrict__ hp1,
              const float* __restrict__ battn, const float* __restrict__ vat,
              const int* __restrict__ mask,
              float* __restrict__ eng, float* __restrict__ mcsc,
              float* __restrict__ numpart) {
  __shared__ _Float16 As[64 * 512];       // XOR-swizzled: byte ^= (row&7)<<4
  __shared__ float hpl[NH], vl[NH], ep[64][8], wl[64];
  int tile = blockIdx.x;                  // 0..2047
  int b = tile >> 5;
  long row0 = (long)tile << 6;
  int tid = threadIdx.x;
  hpl[tid] = hp0[(b << 9) + tid] + hp1[(b << 9) + tid] + battn[tid];
  vl[tid] = vat[tid];
  int w = tid >> 6, l = tid & 63;

  // stage 64x512 fp32 -> f16 LDS (swizzled), 2 batches of 8 float4/thread
  const float4* encp = (const float4*)(enc + row0 * NH);
  for (int half = 0; half < 2; ++half) {
    float4 st[8];
    #pragma unroll
    for (int i = 0; i < 8; ++i) st[i] = encp[tid + ((half * 8 + i) << 9)];
    #pragma unroll
    for (int i = 0; i < 8; ++i) {
      int s = tid + ((half * 8 + i) << 9);
      int r = s >> 7, c4 = s & 127;
      f16x4 h4 = {(_Float16)st[i].x, (_Float16)st[i].y,
                  (_Float16)st[i].z, (_Float16)st[i].w};
      *(f16x4*)((char*)As + (r << 10) + (((c4 << 3)) ^ ((r & 7) << 4))) = h4;
    }
  }
  __syncthreads();

  f32x4 acc[4][4];
  #pragma unroll
  for (int mi = 0; mi < 4; ++mi)
    #pragma unroll
    for (int ni = 0; ni < 4; ++ni) acc[mi][ni] = (f32x4){0.f, 0.f, 0.f, 0.f};

  for (int kc = 0; kc < 16; ++kc) {
    f16x8 a[4], bf[4];
    int kb = (kc << 6) + ((l >> 4) << 4);
    #pragma unroll
    for (int mi = 0; mi < 4; ++mi) {
      int r = (mi << 4) + (l & 15);
      a[mi] = *(const f16x8*)((char*)As + (r << 10) + (kb ^ ((r & 7) << 4)));
    }
    #pragma unroll
    for (int ni = 0; ni < 4; ++ni)
      bf[ni] = *(const f16x8*)(Be + (size_t)((((kc << 5) + (w << 2) + ni) << 6) + l) * 8);
    #pragma unroll
    for (int mi = 0; mi < 4; ++mi)
      #pragma unroll
      for (int ni = 0; ni < 4; ++ni)
        acc[mi][ni] = __builtin_amdgcn_mfma_f32_16x16x32_f16(a[mi], bf[ni], acc[mi][ni], 0, 0, 0);
  }

  // epilogue: e[row] = sum_col v[col]*tanh(acc + hp[col])
  int cl = l & 15;
  #pragma unroll
  for (int mi = 0; mi < 4; ++mi) {
    float s0 = 0.f, s1 = 0.f, s2 = 0.f, s3 = 0.f;
    #pragma unroll
    for (int ni = 0; ni < 4; ++ni) {
      int col = (w << 6) + (ni << 4) + cl;
      float hv = hpl[col], vv = vl[col];
      s0 += vv * fast_tanh(acc[mi][ni][0] + hv);
      s1 += vv * fast_tanh(acc[mi][ni][1] + hv);
      s2 += vv * fast_tanh(acc[mi][ni][2] + hv);
      s3 += vv * fast_tanh(acc[mi][ni][3] + hv);
    }
    #pragma unroll
    for (int off = 1; off < 16; off <<= 1) {
      s0 += __shfl_xor(s0, off, 64);
      s1 += __shfl_xor(s1, off, 64);
      s2 += __shfl_xor(s2, off, 64);
      s3 += __shfl_xor(s3, off, 64);
    }
    if (cl == 0) {
      int rb = (mi << 4) + ((l >> 4) << 2);
      ep[rb][w] = s0; ep[rb + 1][w] = s1; ep[rb + 2][w] = s2; ep[rb + 3][w] = s3;
    }
  }
  __syncthreads();

  // wave 0: finalize 64 energies, chunk max/sum, weights
  if (tid < 64) {
    float e = 0.f;
    #pragma unroll
    for (int q = 0; q < 8; ++q) e += ep[tid][q];
    int mk = mask[row0 + tid];
    e = mk ? e : -3.0e38f;
    eng[row0 + tid] = e;
    float m = e;
    #pragma unroll
    for (int off = 32; off; off >>= 1) m = fmaxf(m, __shfl_xor(m, off, 64));
    float wv = mk ? __expf(e - m) : 0.f;
    float s = wv;
    #pragma unroll
    for (int off = 32; off; off >>= 1) s += __shfl_xor(s, off, 64);
    wl[tid] = wv;
    if (tid == 0) { mcsc[tile * 2] = m; mcsc[tile * 2 + 1] = s; }
  }
  __syncthreads();

  // context partial: thread = one column
  float a = 0.f;
  #pragma unroll 4
  for (int t = 0; t < 64; ++t) {
    float ev = (float)(*(const _Float16*)((char*)As + (t << 10) + (((tid * 2)) ^ ((t & 7) << 4))));
    a += wl[t] * ev;
  }
  numpart[(size_t)tile * NH + tid] = a;
}

// ---------- combine: softmax rebuild -> ctx, attn_weights, xcat0 ----------
__global__ void k_combine(const float* __restrict__ mcsc, const float* __restrict__ numpart,
                          const float* __restrict__ eng, const int* __restrict__ token,
                          const float* __restrict__ emb, const float* __restrict__ h0,
                          _Float16* __restrict__ xcat0, float* __restrict__ attw) {
  __shared__ float scale_s[32], Ms, dens;
  int b = blockIdx.x, tid = threadIdx.x;   // 512 thr
  if (tid < 32) {
    float m = mcsc[(b * 32 + tid) * 2];
    float s = mcsc[(b * 32 + tid) * 2 + 1];
    float M = m;
    #pragma unroll
    for (int off = 16; off; off >>= 1) M = fmaxf(M, __shfl_xor(M, off, 32));
    float sc = __expf(m - M);
    float d = sc * s;
    #pragma unroll
    for (int off = 16; off; off >>= 1) d += __shfl_xor(d, off, 32);
    scale_s[tid] = sc;
    if (tid == 0) { Ms = M; dens = d; }
  }
  __syncthreads();
  float M = Ms, rden = 1.f / dens;
  // context -> xcat0[256:768]
  float a = 0.f;
  #pragma unroll 4
  for (int c = 0; c < 32; ++c) a += scale_s[c] * numpart[(size_t)(b * 32 + c) * NH + tid];
  xcat0[b * 1280 + 256 + tid] = (_Float16)(a * rden);
  // embedding -> xcat0[0:256]
  if (tid < 256) xcat0[b * 1280 + tid] = (_Float16)emb[(size_t)token[b] * NE + tid];
  // h0 layer0 -> xcat0[768:1280]
  xcat0[b * 1280 + 768 + tid] = (_Float16)h0[b * NH + tid];
  // attention weights
  #pragma unroll
  for (int i = 0; i < 4; ++i) {
    int t = tid + (i << 9);
    attw[(b << 11) + t] = __expf(eng[(b << 11) + t] - M) * rden;
  }
}

// ---------- LSTM cell activation (combines gate partials) ----------
// hpitch: row stride of the f16 hidden copy (1024 for xcat1, 512 for h1f)
__global__ void k_act(const float* __restrict__ pg, const float* __restrict__ bih,
                      const float* __restrict__ bhh, const float* __restrict__ cprev,
                      float* __restrict__ hout, float* __restrict__ cout,
                      _Float16* __restrict__ hf16, int hpitch, int nchunks) {
  int idx = blockIdx.x * 256 + threadIdx.x;   // 0..32767
  int b = idx >> 9, u = idx & 511;
  float g[4];
  #pragma unroll
  for (int gi = 0; gi < 4; ++gi) {
    float s = bih[gi * 512 + u] + bhh[gi * 512 + u];
    for (int kc = 0; kc < nchunks; ++kc)
      s += pg[((size_t)kc * 64 + b) * 2048 + gi * 512 + u];
    g[gi] = s;
  }
  float c = fast_sig(g[1]) * cprev[idx] + fast_sig(g[0]) * fast_tanh(g[2]);
  float h = fast_sig(g[3]) * fast_tanh(c);
  cout[idx] = c;
  hout[idx] = h;
  hf16[b * hpitch + u] = (_Float16)h;
}

// ---------- launch ----------
extern "C" void kernel_launch(void* const* d_in, const int* in_sizes, int n_in,
                              void* d_out, int out_size, void* d_ws, size_t ws_size,
                              hipStream_t stream) {
  (void)in_sizes; (void)n_in; (void)out_size; (void)ws_size;
  const int*   token = (const int*)d_in[0];
  const float* h0    = (const float*)d_in[1];
  const float* c0    = (const float*)d_in[2];
  const float* enc   = (const float*)d_in[3];
  const int*   mask  = (const int*)d_in[4];
  const float* emb   = (const float*)d_in[5];
  const float* Wattn = (const float*)d_in[6];
  const float* battn = (const float*)d_in[7];
  const float* vattn = (const float*)d_in[8];
  const float* Wih0  = (const float*)d_in[9];
  const float* Whh0  = (const float*)d_in[10];
  const float* bih0  = (const float*)d_in[11];
  const float* bhh0  = (const float*)d_in[12];
  const float* Wih1  = (const float*)d_in[13];
  const float* Whh1  = (const float*)d_in[14];
  const float* bih1  = (const float*)d_in[15];
  const float* bhh1  = (const float*)d_in[16];
  const float* Wout  = (const float*)d_in[17];
  const float* bout  = (const float*)d_in[18];

  // workspace layout
  float* ws    = (float*)d_ws;
  float* pghp  = ws;                       //  2*64*512   = 65536
  float* eng   = pghp + 65536;             //  131072
  float* mcsc  = eng + 131072;             //  4096
  float* np    = mcsc + 4096;              //  2048*512   = 1048576
  float* pg0   = np + 1048576;             //  4*64*2048  = 524288
  float* pg1   = pg0 + 524288;             //  524288
  _Float16* Be    = (_Float16*)(pg1 + 524288);  // 262144 h
  _Float16* xh    = Be + 262144;                // 64*512
  _Float16* xcat0 = xh + 32768;                 // 64*1280
  _Float16* xcat1 = xcat0 + 81920;              // 64*1024
  _Float16* h1f   = xcat1 + 65536;              // 64*512

  float* out    = (float*)d_out;
  float* logits = out;
  float* hnew   = out + (size_t)NB * NV;
  float* cnew   = hnew + 2 * NB * NH;
  float* attw   = cnew + 2 * NB * NH;

  k_swz_be<<<dim3(128), dim3(256), 0, stream>>>(Wattn, Be);
  k_prep_htop<<<dim3(64), dim3(512), 0, stream>>>(h0, xh, xcat1);
  // h_part: A=htop, B=W_attn[:, :512] (ldb 1024), N=512, 2 chunks of 256
  k_gemm_bT<256><<<dim3(32), dim3(128), 0, stream>>>(
      xh, NH, Wattn, 1024, nullptr, 0, 1 << 30, nullptr, pghp, NH);
  k_energy<<<dim3(2048), dim3(512), 0, stream>>>(
      enc, Be, pghp, pghp + 32768, battn, vattn, mask, eng, mcsc, np);
  k_combine<<<dim3(64), dim3(512), 0, stream>>>(
      mcsc, np, eng, token, emb, h0, xcat0, attw);
  // layer0 gates: A=xcat0 [64x1280], B=[Wih0|Whh0], 4 chunks of 320
  k_gemm_bT<320><<<dim3(256), dim3(128), 0, stream>>>(
      xcat0, 1280, Wih0, 768, Whh0, NH, 768, nullptr, pg0, 2048);
  k_act<<<dim3(128), dim3(256), 0, stream>>>(
      pg0, bih0, bhh0, c0, hnew, cnew, xcat1, 1024, 4);
  // layer1 gates: A=xcat1 [64x1024], B=[Wih1|Whh1], 4 chunks of 256
  k_gemm_bT<256><<<dim3(256), dim3(128), 0, stream>>>(
      xcat1, 1024, Wih1, NH, Whh1, NH, NH, nullptr, pg1, 2048);
  k_act<<<dim3(128), dim3(256), 0, stream>>>(
      pg1, bih1, bhh1, c0 + NB * NH, hnew + NB * NH, cnew + NB * NH, h1f, 512, 4);
  // logits: A=h1 f16, B=Wout (read once), single chunk K=512, bias fused
  k_gemm_bT<512><<<dim3(1000), dim3(128), 0, stream>>>(
      h1f, NH, Wout, NH, nullptr, 0, 1 << 30, bout, logits, NV);
}